// Round 3
// baseline (322.276 us; speedup 1.0000x reference)
//
#include <hip/hip_runtime.h>

// LightshiftaddLayer — ALL inputs float32 per the reference (x (T,B,C),
// shift_W (C,C), shift_b (C), weight (8,7)); output float32 (T,B,C).
// Internally: x and pow2-quantized W cast to bf16 (exact for Wq), bf16 MFMA
// GEMM with fp32 accum, bf16 intermediate Y, fp32 depthwise conv + fp32 out.
constexpr int T_DIM = 4096;
constexpr int B_DIM = 16;
constexpr int C_DIM = 512;
constexpr int K_CONV = 7;
constexpr int M_DIM = T_DIM * B_DIM;   // 65536 GEMM rows
constexpr int BC = B_DIM * C_DIM;      // 8192

typedef __attribute__((ext_vector_type(8))) short bf16x8;
typedef __attribute__((ext_vector_type(4))) float f32x4;
typedef __attribute__((ext_vector_type(8))) float f32x8;
typedef __attribute__((ext_vector_type(4))) unsigned int u32x4;

__device__ __forceinline__ unsigned short f2bf(float f) {
  unsigned u = __float_as_uint(f);
  u += 0x7fffu + ((u >> 16) & 1u);   // RNE
  return (unsigned short)(u >> 16);
}
__device__ __forceinline__ unsigned pack2(float a, float b) {
  return (unsigned)f2bf(a) | (((unsigned)f2bf(b)) << 16);
}

// ---------------------------------------------------------------- cast x -> bf16
__global__ __launch_bounds__(256) void cast_x(
    const float* __restrict__ X, unsigned short* __restrict__ A) {
  long i = (long)(blockIdx.x * 256 + threadIdx.x) * 8;
  f32x4 v0 = *(const f32x4*)(X + i);
  f32x4 v1 = *(const f32x4*)(X + i + 4);
  u32x4 o;
  o[0] = pack2(v0[0], v0[1]);
  o[1] = pack2(v0[2], v0[3]);
  o[2] = pack2(v1[0], v1[1]);
  o[3] = pack2(v1[2], v1[3]);
  *(u32x4*)(A + i) = o;
}

// ---------------------------------------------------------------- quantize W -> bf16
__global__ __launch_bounds__(256) void quantize_w(
    const float* __restrict__ W, unsigned short* __restrict__ Wq) {
  int i = blockIdx.x * 256 + threadIdx.x;
  float w = W[i];
  float a = fabsf(w) + 1e-12f;
  float q = exp2f(rintf(log2f(a)));       // rintf = RNE, matches jnp.round
  q = (w > 0.f) ? q : ((w < 0.f) ? -q : 0.f);
  Wq[i] = f2bf(q);                        // powers of two: exact in bf16
}

// ---------------------------------------------------------------- GEMM (B^T)
// Y[m,n] = sum_k A[m,k]*Bt[n,k] + bias[n]; A=(65536,512) bf16, Bt=(512,512) bf16.
constexpr int BK = 32;

__global__ __launch_bounds__(256, 2) void gemm_bt(
    const short* __restrict__ A, const short* __restrict__ Bt,
    const float* __restrict__ bias, unsigned short* __restrict__ Y) {
  constexpr int K = C_DIM, N = C_DIM;
  __shared__ __align__(16) short As[128 * BK];   // 8 KB
  __shared__ __align__(16) short Bs[128 * BK];   // 8 KB

  const int t    = threadIdx.x;
  const int lane = t & 63;
  const int wid  = t >> 6;               // 4 waves: 2x2 of 64x64
  const int m0 = blockIdx.y * 128;
  const int n0 = blockIdx.x * 128;

  // staging: 4 threads per 64-byte row
  const int sr = t >> 2;                 // 0..63
  const int sc = (t & 3) * 8;
  const short* pA0 = A  + (long)(m0 + sr) * K + sc;
  const short* pA1 = A  + (long)(m0 + 64 + sr) * K + sc;
  const short* pB0 = Bt + (long)(n0 + sr) * K + sc;
  const short* pB1 = Bt + (long)(n0 + 64 + sr) * K + sc;

  // fragment indices (A frag: A[m=lane&15][k=(lane>>4)*8+j])
  const int fr = lane & 15;
  const int fq = lane >> 4;
  const int wm = (wid >> 1) * 64;
  const int wn = (wid & 1) * 64;

  f32x4 acc[4][4] = {};

  for (int k0 = 0; k0 < K; k0 += BK) {
    bf16x8 a0 = *(const bf16x8*)(pA0 + k0);
    bf16x8 a1 = *(const bf16x8*)(pA1 + k0);
    bf16x8 b0 = *(const bf16x8*)(pB0 + k0);
    bf16x8 b1 = *(const bf16x8*)(pB1 + k0);
    __syncthreads();                       // prev iter's LDS reads done
    *(bf16x8*)&As[sr * BK + sc]        = a0;
    *(bf16x8*)&As[(64 + sr) * BK + sc] = a1;
    *(bf16x8*)&Bs[sr * BK + sc]        = b0;
    *(bf16x8*)&Bs[(64 + sr) * BK + sc] = b1;
    __syncthreads();                       // staging visible

    bf16x8 af[4], bfr[4];
#pragma unroll
    for (int i = 0; i < 4; ++i)
      af[i] = *(const bf16x8*)&As[(wm + i * 16 + fr) * BK + fq * 8];
#pragma unroll
    for (int j = 0; j < 4; ++j)
      bfr[j] = *(const bf16x8*)&Bs[(wn + j * 16 + fr) * BK + fq * 8];
#pragma unroll
    for (int i = 0; i < 4; ++i)
#pragma unroll
      for (int j = 0; j < 4; ++j)
        acc[i][j] = __builtin_amdgcn_mfma_f32_16x16x32_bf16(af[i], bfr[j], acc[i][j], 0, 0, 0);
  }

  // epilogue: C/D layout col=lane&15, row=(lane>>4)*4+reg
#pragma unroll
  for (int j = 0; j < 4; ++j) {
    const int gn = n0 + wn + j * 16 + fr;
    const float bv = bias[gn];
#pragma unroll
    for (int i = 0; i < 4; ++i) {
#pragma unroll
      for (int r = 0; r < 4; ++r) {
        const int gm = m0 + wm + i * 16 + fq * 4 + r;
        Y[(long)gm * N + gn] = f2bf(acc[i][j][r] + bv);
      }
    }
  }
}

// ---------------------------------------------------------------- depthwise conv
// out[t,b,c] = sum_k y[t+k-3,b,c] * softmax(weight[h])[k], h = c>>6.
constexpr int CHT = 16;   // t's per thread

__device__ __forceinline__ u32x4 loadY(const unsigned short* Y, int t, long off) {
  if ((unsigned)t < (unsigned)T_DIM)
    return *(const u32x4*)(Y + (long)t * BC + off);
  u32x4 z = {0u, 0u, 0u, 0u};
  return z;
}

__device__ __forceinline__ f32x8 unpack8(u32x4 u) {
  f32x8 r;
#pragma unroll
  for (int i = 0; i < 4; ++i) {
    unsigned w = u[i];
    r[2 * i]     = __uint_as_float(w << 16);
    r[2 * i + 1] = __uint_as_float(w & 0xffff0000u);
  }
  return r;
}

__global__ __launch_bounds__(256) void lconv(
    const unsigned short* __restrict__ Y, const float* __restrict__ W,
    float* __restrict__ O) {
  const int tid  = blockIdx.x * 256 + threadIdx.x;
  const int cvec = tid & 63;               // 8-channel vector index
  const int b    = (tid >> 6) & 15;
  const int tc   = tid >> 10;              // t chunk
  const int t0   = tc * CHT;
  const long off = (long)b * C_DIM + cvec * 8;
  const int h    = cvec >> 3;              // head = c/64

  // softmax over the head's 7 taps (fp32, matches ref exactly)
  float wf[K_CONV];
  float mx = -1e30f;
#pragma unroll
  for (int k = 0; k < K_CONV; ++k) { wf[k] = W[h * K_CONV + k]; mx = fmaxf(mx, wf[k]); }
  float s = 0.f;
#pragma unroll
  for (int k = 0; k < K_CONV; ++k) { wf[k] = __expf(wf[k] - mx); s += wf[k]; }
  const float inv = 1.f / s;
#pragma unroll
  for (int k = 0; k < K_CONV; ++k) wf[k] *= inv;

  f32x8 win[K_CONV];
#pragma unroll
  for (int i = 0; i < 6; ++i) win[i] = unpack8(loadY(Y, t0 - 3 + i, off));

#pragma unroll
  for (int j = 0; j < CHT; ++j) {
    win[6] = unpack8(loadY(Y, t0 + 3 + j, off));
    f32x8 acc = win[0] * wf[0];
#pragma unroll
    for (int k = 1; k < K_CONV; ++k) acc += win[k] * wf[k];
    float* op = O + (long)(t0 + j) * BC + off;
    *(f32x4*)op       = f32x4{acc[0], acc[1], acc[2], acc[3]};
    *(f32x4*)(op + 4) = f32x4{acc[4], acc[5], acc[6], acc[7]};
#pragma unroll
    for (int k = 0; k < 6; ++k) win[k] = win[k + 1];
  }
}

// ---------------------------------------------------------------- launch
extern "C" void kernel_launch(void* const* d_in, const int* in_sizes, int n_in,
                              void* d_out, int out_size, void* d_ws, size_t ws_size,
                              hipStream_t stream) {
  const float* x       = (const float*)d_in[0];  // (T,B,C) fp32
  const float* shift_W = (const float*)d_in[1];  // (C,C) fp32
  const float* shift_b = (const float*)d_in[2];  // (C) fp32
  const float* weight  = (const float*)d_in[3];  // (8,7) fp32
  float* out = (float*)d_out;

  unsigned short* A  = (unsigned short*)d_ws;        // 64 MB bf16 x
  unsigned short* Wq = A + (long)M_DIM * C_DIM;      // 512 KB bf16 Wq
  unsigned short* Y  = Wq + C_DIM * C_DIM;           // 64 MB bf16 y

  cast_x<<<(long)M_DIM * C_DIM / (256 * 8), 256, 0, stream>>>(x, A);
  quantize_w<<<(C_DIM * C_DIM) / 256, 256, 0, stream>>>(shift_W, Wq);
  gemm_bt<<<dim3(C_DIM / 128, M_DIM / 128), 256, 0, stream>>>(
      (const short*)A, (const short*)Wq, shift_b, Y);
  lconv<<<(M_DIM / CHT) * (C_DIM / 8) / 256, 256, 0, stream>>>(Y, weight, out);
}